// Round 2
// baseline (244.076 us; speedup 1.0000x reference)
//
#include <hip/hip_runtime.h>

// LIF/IF activation, T=4, v_th=1, subtractive reset, ATan surrogate (fwd only).
// out = (sum_{t=1..4} H(v_t - 1)) / 4 * safe_scale, with
//   c = relu(x) / safe_scale;  v <- v + c;  s = H(v-1);  v <- v - s.
// Arithmetic replicated step-by-step in fp32 to match the numpy reference
// bit-for-bit (IEEE division, no reciprocal-multiply: a 1-ulp difference in c
// can flip a spike at a threshold crossing, costing 0.375 absmax).
//
// MLP restructure: each thread issues UNROLL=8 independent 16B loads
// back-to-back (128 B/lane in flight) before any compute, then computes and
// streams nontemporal stores (output has zero reuse; keep the write stream
// from thrashing L2/L3 against the input stream).
//
// NOTE: __builtin_nontemporal_store requires a native clang vector type, not
// HIP's float4 class — hence the ext_vector_type typedef.

#define THREADS 256
#define UNROLL 8

typedef float f32x4 __attribute__((ext_vector_type(4)));

__device__ __forceinline__ float lif_elem(float x, float safe_scale) {
    float c = fmaxf(x, 0.0f) / safe_scale;   // IEEE-correct fp32 division at -O3 (no fast-math)
    float v = 0.0f;
    float cnt = 0.0f;
#pragma unroll
    for (int t = 0; t < 4; ++t) {
        v += c;
        float s = ((v - 1.0f) >= 0.0f) ? 1.0f : 0.0f;  // H(v - v_th), v_th = 1
        v -= s;
        cnt += s;
    }
    return (cnt * 0.25f) * safe_scale;       // mean over T, then rescale (ref order)
}

__device__ __forceinline__ f32x4 lif_vec(f32x4 xv, float ss) {
    f32x4 ov;
    ov.x = lif_elem(xv.x, ss);
    ov.y = lif_elem(xv.y, ss);
    ov.z = lif_elem(xv.z, ss);
    ov.w = lif_elem(xv.w, ss);
    return ov;
}

__global__ __launch_bounds__(THREADS) void lif_kernel(const f32x4* __restrict__ x,
                                                      const float* __restrict__ scale_p,
                                                      f32x4* __restrict__ out,
                                                      int n4) {
    const float ss = fmaxf(scale_p[0], 1e-12f);  // uniform scalar, s_load + SALU
    const int nth = gridDim.x * THREADS;          // total threads
    int i = blockIdx.x * THREADS + threadIdx.x;

    // Main loop: UNROLL independent float4 streams per thread, loads issued
    // before any compute so the wave has 8 outstanding vmem ops.
    // Grid is sized so this executes exactly once for the bench shape;
    // the loop form keeps it correct for any n4.
    for (; i + (UNROLL - 1) * nth < n4; i += UNROLL * nth) {
        f32x4 xv[UNROLL];
#pragma unroll
        for (int u = 0; u < UNROLL; ++u) {
            xv[u] = x[i + u * nth];               // coalesced: lane-consecutive 16B
        }
#pragma unroll
        for (int u = 0; u < UNROLL; ++u) {
            f32x4 ov = lif_vec(xv[u], ss);
            __builtin_nontemporal_store(ov, &out[i + u * nth]);
        }
    }
    // Remainder (n4 not a multiple of UNROLL*nth): one float4 per pass.
    for (; i < n4; i += nth) {
        f32x4 ov = lif_vec(x[i], ss);
        __builtin_nontemporal_store(ov, &out[i]);
    }
}

// Tail handler for n % 4 != 0 (not hit for 4096x8192, kept for safety).
__global__ void lif_tail_kernel(const float* __restrict__ x,
                                const float* __restrict__ scale_p,
                                float* __restrict__ out,
                                int start, int n) {
    int idx = start + blockIdx.x * blockDim.x + threadIdx.x;
    if (idx >= n) return;
    float safe_scale = fmaxf(scale_p[0], 1e-12f);
    out[idx] = lif_elem(x[idx], safe_scale);
}

extern "C" void kernel_launch(void* const* d_in, const int* in_sizes, int n_in,
                              void* d_out, int out_size, void* d_ws, size_t ws_size,
                              hipStream_t stream) {
    const float* x = (const float*)d_in[0];
    const float* scale = (const float*)d_in[1];
    float* out = (float*)d_out;
    int n = in_sizes[0];
    int n4 = n >> 2;

    if (n4 > 0) {
        // One UNROLL-batch per thread: 8M float4 / (256 thr * 8) = 4096 blocks
        // for the bench shape (16 blocks/CU, plenty of waves to saturate HBM).
        long long per_block = (long long)THREADS * UNROLL;
        int blocks = (int)((n4 + per_block - 1) / per_block);
        if (blocks < 1) blocks = 1;
        lif_kernel<<<blocks, THREADS, 0, stream>>>((const f32x4*)x, scale,
                                                   (f32x4*)out, n4);
    }
    int tail_start = n4 << 2;
    int tail = n - tail_start;
    if (tail > 0) {
        lif_tail_kernel<<<1, 64, 0, stream>>>(x, scale, out, tail_start, n);
    }
}

// Round 3
// 229.935 us; speedup vs baseline: 1.0615x; 1.0615x over previous
//
#include <hip/hip_runtime.h>

// LIF/IF activation, T=4, v_th=1, subtractive reset, ATan surrogate (fwd only).
// out = (sum_{t=1..4} H(v_t - 1)) / 4 * safe_scale, with
//   c = relu(x) / safe_scale;  v <- v + c;  s = H(v-1);  v <- v - s.
// Arithmetic replicated step-by-step in fp32 to match the numpy reference
// bit-for-bit (IEEE division, no reciprocal-multiply: a 1-ulp difference in c
// can flip a spike at a threshold crossing, costing 0.375 absmax).
//
// Round-2 post-mortem: 16MB-stride MLP + nontemporal stores REGRESSED
// (98 µs @ 2 TB/s, VALU 25%, hbm 25% — issue-limited, compiler re-serialized
// at 36 VGPRs). This revision: block-contiguous unroll (block owns a 16 KB
// tile; each of the 4 loads is one contiguous 4 KB wave-chunk issued
// back-to-back), plain write-back stores (the 6.6 TB/s fill kernel uses
// plain stores), grid = 8192 blocks (32/CU).

#define THREADS 256
#define UNROLL 4

typedef float f32x4 __attribute__((ext_vector_type(4)));

__device__ __forceinline__ float lif_elem(float x, float safe_scale) {
    float c = fmaxf(x, 0.0f) / safe_scale;   // IEEE-correct fp32 division at -O3 (no fast-math)
    float v = 0.0f;
    float cnt = 0.0f;
#pragma unroll
    for (int t = 0; t < 4; ++t) {
        v += c;
        float s = ((v - 1.0f) >= 0.0f) ? 1.0f : 0.0f;  // H(v - v_th), v_th = 1
        v -= s;
        cnt += s;
    }
    return (cnt * 0.25f) * safe_scale;       // mean over T, then rescale (ref order)
}

__device__ __forceinline__ f32x4 lif_vec(f32x4 xv, float ss) {
    f32x4 ov;
    ov.x = lif_elem(xv.x, ss);
    ov.y = lif_elem(xv.y, ss);
    ov.z = lif_elem(xv.z, ss);
    ov.w = lif_elem(xv.w, ss);
    return ov;
}

__global__ __launch_bounds__(THREADS) void lif_kernel(const f32x4* __restrict__ x,
                                                      const float* __restrict__ scale_p,
                                                      f32x4* __restrict__ out,
                                                      int n4) {
    const float ss = fmaxf(scale_p[0], 1e-12f);    // uniform scalar (s_load)
    const int tile = THREADS * UNROLL;             // 1024 float4 = 16 KB per block
    int base = blockIdx.x * tile + threadIdx.x;

    if (base + (UNROLL - 1) * THREADS < n4) {
        // Fast path: whole tile in range. 4 contiguous-4KB loads issued
        // back-to-back (4 outstanding vmem ops per wave), then compute+store.
        f32x4 xv[UNROLL];
#pragma unroll
        for (int u = 0; u < UNROLL; ++u) {
            xv[u] = x[base + u * THREADS];
        }
#pragma unroll
        for (int u = 0; u < UNROLL; ++u) {
            out[base + u * THREADS] = lif_vec(xv[u], ss);
        }
    } else {
        // Edge tile (not hit for the bench shape: 8M % 1024 == 0).
#pragma unroll
        for (int u = 0; u < UNROLL; ++u) {
            int i = base + u * THREADS;
            if (i < n4) out[i] = lif_vec(x[i], ss);
        }
    }
}

// Tail handler for n % 4 != 0 (not hit for 4096x8192, kept for safety).
__global__ void lif_tail_kernel(const float* __restrict__ x,
                                const float* __restrict__ scale_p,
                                float* __restrict__ out,
                                int start, int n) {
    int idx = start + blockIdx.x * blockDim.x + threadIdx.x;
    if (idx >= n) return;
    float safe_scale = fmaxf(scale_p[0], 1e-12f);
    out[idx] = lif_elem(x[idx], safe_scale);
}

extern "C" void kernel_launch(void* const* d_in, const int* in_sizes, int n_in,
                              void* d_out, int out_size, void* d_ws, size_t ws_size,
                              hipStream_t stream) {
    const float* x = (const float*)d_in[0];
    const float* scale = (const float*)d_in[1];
    float* out = (float*)d_out;
    int n = in_sizes[0];
    int n4 = n >> 2;

    if (n4 > 0) {
        int tile = THREADS * UNROLL;                    // 1024 float4 per block
        int blocks = (n4 + tile - 1) / tile;            // 8192 for bench shape
        lif_kernel<<<blocks, THREADS, 0, stream>>>((const f32x4*)x, scale,
                                                   (f32x4*)out, n4);
    }
    int tail_start = n4 << 2;
    int tail = n - tail_start;
    if (tail > 0) {
        lif_tail_kernel<<<1, 64, 0, stream>>>(x, scale, out, tail_start, n);
    }
}